// Round 1
// baseline (401.557 us; speedup 1.0000x reference)
//
#include <hip/hip_runtime.h>
#include <math.h>

// CircleLoss fused: sim = x_norm @ x_norm^T, per-row exp-sums over
// positives/negatives, loss = mean(log1p(sumP*sumN)).
// Bound analysis: -logit_p in [-252, 4], logit_n in [0, 36] -> direct
// exp-sum in f32 is safe (no overflow; sumP,sumN never 0), so no
// max-tracking logsumexp needed.

#define NROWS 8192
#define DIM   128
#define BI 64
#define BJ 64
#define SLDS 132   // padded LDS stride (floats): A-reads conflict-free, B-reads 2-way (free)
#define NJ 8       // j-dimension block splits -> grid = 128 x 8 = 1024 blocks

// ws layout:
// [0, 4MB)            : xn  f32 [NROWS][DIM]  (L2-normalized rows)
// [4MB, 4MB+32KB)     : gP  f32 [NROWS]       (sum of exp(-logit_p) over positives)
// [4MB+32KB, 4MB+64KB): gN  f32 [NROWS]       (sum of exp(logit_n) over negatives)

__global__ __launch_bounds__(256) void normalize_kernel(
    const float* __restrict__ x, float* __restrict__ xn) {
  const int wave = threadIdx.x >> 6;
  const int lane = threadIdx.x & 63;
  const int row  = blockIdx.x * 4 + wave;
  const float2 v = ((const float2*)(x + (size_t)row * DIM))[lane];
  float ss = v.x * v.x + v.y * v.y;
  #pragma unroll
  for (int m = 1; m < 64; m <<= 1) ss += __shfl_xor(ss, m);
  const float r = rsqrtf(ss);
  float2 o; o.x = v.x * r; o.y = v.y * r;
  ((float2*)(xn + (size_t)row * DIM))[lane] = o;
}

__global__ __launch_bounds__(256) void simloss_kernel(
    const float* __restrict__ xn, const int* __restrict__ tgt,
    float* __restrict__ gP, float* __restrict__ gN) {
  __shared__ float As[BI * SLDS];
  __shared__ float Bs[BJ * SLDS];
  __shared__ int tA[BI];
  __shared__ int tB[BJ];

  const int i0  = blockIdx.x * BI;
  const int tid = threadIdx.x;
  const int tx  = tid & 15;   // j sub-index
  const int ty  = tid >> 4;   // i sub-index

  // Stage A rows (once per block), coalesced float4
  for (int idx = tid; idx < BI * (DIM / 4); idx += 256) {
    const int r = idx >> 5, c = idx & 31;
    const float4 v = ((const float4*)(xn + (size_t)(i0 + r) * DIM))[c];
    *((float4*)&As[r * SLDS + c * 4]) = v;
  }
  if (tid < BI) tA[tid] = tgt[i0 + tid];

  float sp[4] = {0.f, 0.f, 0.f, 0.f};
  float sn[4] = {0.f, 0.f, 0.f, 0.f};

  const int j0base = blockIdx.y * (NROWS / NJ);
  const int jtiles = (NROWS / NJ) / BJ;

  for (int t = 0; t < jtiles; ++t) {
    const int j0 = j0base + t * BJ;
    __syncthreads();  // protect Bs/tB from previous-iteration readers (also covers As on t==0)
    for (int idx = tid; idx < BJ * (DIM / 4); idx += 256) {
      const int r = idx >> 5, c = idx & 31;
      const float4 v = ((const float4*)(xn + (size_t)(j0 + r) * DIM))[c];
      *((float4*)&Bs[r * SLDS + c * 4]) = v;
    }
    if (tid < BJ) tB[tid] = tgt[j0 + tid];
    __syncthreads();

    float acc[4][4] = {};
    #pragma unroll 4
    for (int k4 = 0; k4 < DIM / 4; ++k4) {
      float4 a[4], b[4];
      #pragma unroll
      for (int r = 0; r < 4; ++r)
        a[r] = *((const float4*)&As[(ty + 16 * r) * SLDS + k4 * 4]);
      #pragma unroll
      for (int c = 0; c < 4; ++c)
        b[c] = *((const float4*)&Bs[(tx + 16 * c) * SLDS + k4 * 4]);
      #pragma unroll
      for (int r = 0; r < 4; ++r)
        #pragma unroll
        for (int c = 0; c < 4; ++c)
          acc[r][c] += a[r].x * b[c].x + a[r].y * b[c].y +
                       a[r].z * b[c].z + a[r].w * b[c].w;
    }

    // Fused epilogue: one exp per sim element (branchless select)
    #pragma unroll
    for (int r = 0; r < 4; ++r) {
      const int ta = tA[ty + 16 * r];
      #pragma unroll
      for (int c = 0; c < 4; ++c) {
        const float s = acc[r][c];
        const bool pos = (ta == tB[tx + 16 * c]);
        const float ap = fmaxf(1.25f - s, 0.f);
        const float an = fmaxf(s - 0.25f, 0.f);
        const float ep = ap * (s - 0.75f) * 64.f;  // -logit_p
        const float en = an * an * 64.f;           // logit_n = 64*an^2
        const float e = __expf(pos ? ep : en);
        sp[r] += pos ? e : 0.f;
        sn[r] += pos ? 0.f : e;
      }
    }
  }

  // Reduce across the 16 tx-lanes (same 16-lane group within a wave)
  #pragma unroll
  for (int r = 0; r < 4; ++r) {
    #pragma unroll
    for (int m = 1; m < 16; m <<= 1) {
      sp[r] += __shfl_xor(sp[r], m);
      sn[r] += __shfl_xor(sn[r], m);
    }
  }
  if (tx == 0) {
    #pragma unroll
    for (int r = 0; r < 4; ++r) {
      atomicAdd(&gP[i0 + ty + 16 * r], sp[r]);
      atomicAdd(&gN[i0 + ty + 16 * r], sn[r]);
    }
  }
}

__global__ __launch_bounds__(256) void finalize_kernel(
    const float* __restrict__ gP, const float* __restrict__ gN,
    float* __restrict__ out) {
  __shared__ float red[256];
  float local = 0.f;
  for (int i = threadIdx.x; i < NROWS; i += 256) {
    local += log1pf(gP[i] * gN[i]);  // softplus(lp+ln) = log1p(sumP*sumN)
  }
  red[threadIdx.x] = local;
  __syncthreads();
  for (int s = 128; s > 0; s >>= 1) {
    if (threadIdx.x < s) red[threadIdx.x] += red[threadIdx.x + s];
    __syncthreads();
  }
  if (threadIdx.x == 0) out[0] = red[0] / (float)NROWS;
}

extern "C" void kernel_launch(void* const* d_in, const int* in_sizes, int n_in,
                              void* d_out, int out_size, void* d_ws, size_t ws_size,
                              hipStream_t stream) {
  const float* x  = (const float*)d_in[0];
  const int* tgt  = (const int*)d_in[1];
  float* out      = (float*)d_out;

  float* xn = (float*)d_ws;
  float* gP = (float*)((char*)d_ws + (size_t)NROWS * DIM * sizeof(float));
  float* gN = gP + NROWS;

  hipMemsetAsync(gP, 0, 2 * NROWS * sizeof(float), stream);
  normalize_kernel<<<NROWS / 4, 256, 0, stream>>>(x, xn);
  dim3 grid(NROWS / BI, NJ);
  simloss_kernel<<<grid, 256, 0, stream>>>(xn, tgt, gP, gN);
  finalize_kernel<<<1, 256, 0, stream>>>(gP, gN, out);
}

// Round 2
// 182.356 us; speedup vs baseline: 2.2020x; 2.2020x over previous
//
#include <hip/hip_runtime.h>
#include <math.h>

// CircleLoss fused, MFMA version.
// sim = xn @ xn^T via split-bf16: xn = hi + lo (bf16 each);
// sim ~= hi*hi + hi*lo + lo*hi  (drops lo*lo <= 2^-18 -- negligible vs 0.26 thr).
// Per-row exp-sums over positives/negatives, loss = mean(log1p(sumP*sumN)).
// (-logit_p in [-252,4], logit_n in [0,36] -> f32 exp-sums safe, no max tracking.)

#define NR   8192
#define DIMK 128

typedef __attribute__((ext_vector_type(8))) short short8;   // 8 bf16 (4 VGPRs)
typedef __attribute__((ext_vector_type(4))) float f32x4;

typedef __attribute__((address_space(3))) uint32_t lds_u32;
typedef const __attribute__((address_space(1))) uint32_t glb_u32;

__device__ __forceinline__ unsigned short bf16_rne(float f) {
  uint32_t u = __float_as_uint(f);
  u += 0x7FFFu + ((u >> 16) & 1u);
  return (unsigned short)(u >> 16);
}

// ws layout:
// [0, 2MB)        : xhi  bf16 [NR][DIMK]
// [2MB, 4MB)      : xlo  bf16 [NR][DIMK]
// [4MB, +32KB)    : gP   f32 [NR]
// [.., +32KB)     : gN   f32 [NR]

__global__ __launch_bounds__(256) void normalize_split_kernel(
    const float* __restrict__ x, unsigned short* __restrict__ xhi,
    unsigned short* __restrict__ xlo) {
  const int wave = threadIdx.x >> 6;
  const int lane = threadIdx.x & 63;
  const int row  = blockIdx.x * 4 + wave;
  const float2 v = ((const float2*)(x + (size_t)row * DIMK))[lane];
  float ss = v.x * v.x + v.y * v.y;
  #pragma unroll
  for (int m = 1; m < 64; m <<= 1) ss += __shfl_xor(ss, m);
  const float r = rsqrtf(ss);
  const float a = v.x * r, b = v.y * r;
  const unsigned short ha = bf16_rne(a), hb = bf16_rne(b);
  const float haf = __uint_as_float((uint32_t)ha << 16);
  const float hbf = __uint_as_float((uint32_t)hb << 16);
  ushort2 hi, lo;
  hi.x = ha; hi.y = hb;
  lo.x = bf16_rne(a - haf); lo.y = bf16_rne(b - hbf);
  ((ushort2*)xhi)[(size_t)row * 64 + lane] = hi;
  ((ushort2*)xlo)[(size_t)row * 64 + lane] = lo;
}

__global__ __launch_bounds__(256) void simloss_kernel(
    const unsigned short* __restrict__ xhi, const unsigned short* __restrict__ xlo,
    const int* __restrict__ tgt, float* __restrict__ gP, float* __restrict__ gN) {
  __shared__ unsigned short As[128 * 32];  // [row][k] row-major, 64B rows
  __shared__ unsigned short Bs[128 * 32];
  __shared__ int tAs[128], tBs[128];

  const int tid  = threadIdx.x;
  const int wave = tid >> 6, lane = tid & 63;
  const int wy = wave >> 1, wx = wave & 1;
  const int i0 = blockIdx.x * 128, j0 = blockIdx.y * 128;

  if (tid < 128) tAs[tid] = tgt[i0 + tid];
  else           tBs[tid - 128] = tgt[j0 + tid - 128];

  f32x4 acc[4][4];
  #pragma unroll
  for (int r = 0; r < 4; ++r)
    #pragma unroll
    for (int c = 0; c < 4; ++c)
      acc[r][c] = (f32x4){0.f, 0.f, 0.f, 0.f};

  // Staging decomposition: lane covers 16B; seg(1KB) = 16 rows of 64B.
  const int srow  = lane >> 2;        // row within seg
  const int skcol = (lane & 3) * 8;   // bf16 col within row

  for (int p = 0; p < 3; ++p) {
    const unsigned short* sA = (p == 2) ? xlo : xhi;  // products: (hi,hi),(hi,lo),(lo,hi)
    const unsigned short* sB = (p == 1) ? xlo : xhi;
    for (int kc = 0; kc < 4; ++kc) {
      __syncthreads();  // previous readers done before overwrite (also orders tAs/tBs)
      #pragma unroll
      for (int q = 0; q < 2; ++q) {
        const int seg = wave * 2 + q;
        const int row = seg * 16 + srow;
        const unsigned short* gA = sA + (size_t)(i0 + row) * DIMK + kc * 32 + skcol;
        const unsigned short* gB = sB + (size_t)(j0 + row) * DIMK + kc * 32 + skcol;
        __builtin_amdgcn_global_load_lds((glb_u32*)gA, (lds_u32*)&As[seg * 512], 16, 0, 0);
        __builtin_amdgcn_global_load_lds((glb_u32*)gB, (lds_u32*)&Bs[seg * 512], 16, 0, 0);
      }
      __syncthreads();

      short8 a[4], b[4];
      #pragma unroll
      for (int r = 0; r < 4; ++r)
        a[r] = *(const short8*)&As[(wy * 64 + r * 16 + (lane & 15)) * 32 + (lane >> 4) * 8];
      #pragma unroll
      for (int c = 0; c < 4; ++c)
        b[c] = *(const short8*)&Bs[(wx * 64 + c * 16 + (lane & 15)) * 32 + (lane >> 4) * 8];
      #pragma unroll
      for (int r = 0; r < 4; ++r)
        #pragma unroll
        for (int c = 0; c < 4; ++c)
          acc[r][c] = __builtin_amdgcn_mfma_f32_16x16x32_bf16(a[r], b[c], acc[r][c], 0, 0, 0);
    }
  }

  // Fused epilogue. C layout: col = lane&15, row = (lane>>4)*4 + reg.
  const int q  = lane >> 4;
  const int ci = lane & 15;

  int tb[4];
  #pragma unroll
  for (int c = 0; c < 4; ++c) tb[c] = tBs[wx * 64 + c * 16 + ci];

  #pragma unroll
  for (int r = 0; r < 4; ++r) {
    #pragma unroll
    for (int reg = 0; reg < 4; ++reg) {
      const int ta = tAs[wy * 64 + r * 16 + q * 4 + reg];
      float vsp = 0.f, vsn = 0.f;
      #pragma unroll
      for (int c = 0; c < 4; ++c) {
        const float s  = acc[r][c][reg];
        const bool pos = (ta == tb[c]);
        const float ap = fmaxf(1.25f - s, 0.f);
        const float an = fmaxf(s - 0.25f, 0.f);
        const float argp = ap * fmaf(s, 64.f, -48.f);  // -logit_p = 64*ap*(s-0.75)
        const float argn = an * an * 64.f;             // logit_n  = 64*an^2
        const float e = __expf(pos ? argp : argn);
        vsp += pos ? e : 0.f;
        vsn += pos ? 0.f : e;
      }
      // reduce over the 16 lanes sharing this output row
      #pragma unroll
      for (int m = 1; m < 16; m <<= 1) {
        vsp += __shfl_xor(vsp, m);
        vsn += __shfl_xor(vsn, m);
      }
      if (ci == 0) {
        const int row = i0 + wy * 64 + r * 16 + q * 4 + reg;
        atomicAdd(&gP[row], vsp);
        atomicAdd(&gN[row], vsn);
      }
    }
  }
}

__global__ __launch_bounds__(256) void finalize_kernel(
    const float* __restrict__ gP, const float* __restrict__ gN,
    float* __restrict__ out) {
  __shared__ float red[256];
  float local = 0.f;
  for (int i = threadIdx.x; i < NR; i += 256) {
    local += log1pf(gP[i] * gN[i]);  // softplus(lp+ln) = log1p(sumP*sumN)
  }
  red[threadIdx.x] = local;
  __syncthreads();
  for (int s = 128; s > 0; s >>= 1) {
    if (threadIdx.x < s) red[threadIdx.x] += red[threadIdx.x + s];
    __syncthreads();
  }
  if (threadIdx.x == 0) out[0] = red[0] / (float)NR;
}

extern "C" void kernel_launch(void* const* d_in, const int* in_sizes, int n_in,
                              void* d_out, int out_size, void* d_ws, size_t ws_size,
                              hipStream_t stream) {
  const float* x  = (const float*)d_in[0];
  const int* tgt  = (const int*)d_in[1];
  float* out      = (float*)d_out;

  unsigned short* xhi = (unsigned short*)d_ws;
  unsigned short* xlo = xhi + (size_t)NR * DIMK;
  float* gP = (float*)((char*)d_ws + (size_t)NR * DIMK * 4);  // after 2x bf16 arrays (4MB)
  float* gN = gP + NR;

  hipMemsetAsync(gP, 0, 2 * NR * sizeof(float), stream);
  normalize_split_kernel<<<NR / 4, 256, 0, stream>>>(x, xhi, xlo);
  dim3 grid(NR / 128, NR / 128);
  simloss_kernel<<<grid, 256, 0, stream>>>(xhi, xlo, tgt, gP, gN);
  finalize_kernel<<<1, 256, 0, stream>>>(gP, gN, out);
}